// Round 4
// baseline (1666.513 us; speedup 1.0000x reference)
//
#include <hip/hip_runtime.h>
#include <math.h>

// ---------------------------------------------------------------------------
// DiscriminatorLSTM: B=128, T=64, FEAT=4096, FUSION=1024, H=1024, C=2
//
// Phase A (MFMA): Fh/Fl[8192,1024] = split(relu(X @ W_feat^T + b_feat))
// Phase B (MFMA): Gx[8192,4096]    = (Fh+Fl) @ W_ih^T + b_ih   (f32 out)
// pack_whh: W_hh -> split-bf16 B-fragment layout (16 MB)
// Phase C (per step t):
//   gate_partial (t>0): 256 WGs, K-split x4. WG (ng,kh,mh) computes the
//     partial gate tile over K-slice kh*256..+256 -> P[kh][g][row][col].
//     W fragments read exactly once device-wide (16 MB/step); h fragments
//     staged to LDS once per WG and shared by the 4 gate-waves.
//   cell_cls: 64 WGs reduce partials + Gx + b_hh, apply LSTM cell, write
//     h hi/lo fragments + c, and classifier partials (shfl + atomicAdd).
//
// Workspace (within proven 160 MB):
//   [0,16M)        Wf (after phase B; aliases Fh)
//   [16M,17M)      hfrag double buffer
//   [17M,17.5M)    c        (17825792)
//   [18.5M,26.5M)  P partials (19398656, 8 MB)
//   [32M,160M)     Gx
// ---------------------------------------------------------------------------

typedef __attribute__((ext_vector_type(8))) short short8v;   // 8 bf16
typedef __attribute__((ext_vector_type(4))) float f32x4;

#define WF_LO_OFF 8388608u
#define HF_BUF    524288
#define HF_HL     262144
#define HF_MT     32768
#define P_OFF     19398656u

__device__ __forceinline__ unsigned short f2bf(float f) {   // RNE f32->bf16
    unsigned u = __builtin_bit_cast(unsigned, f);
    u = (u + 0x7fffu + ((u >> 16) & 1u)) >> 16;
    return (unsigned short)u;
}
__device__ __forceinline__ float bf2f(unsigned short b) {
    unsigned u = ((unsigned)b) << 16;
    return __builtin_bit_cast(float, u);
}
__device__ __forceinline__ void split8(const float* f, short8v& hi, short8v& lo) {
#pragma unroll
    for (int e = 0; e < 8; ++e) {
        unsigned short h = f2bf(f[e]);
        hi[e] = (short)h;
        lo[e] = (short)f2bf(f[e] - bf2f(h));
    }
}

// ------------------- split-bf16 MFMA GEMM  (C = A @ B^T) -------------------
template<bool A_SPLIT, bool RELU, bool OUT_SPLIT>
__global__ __launch_bounds__(256)
void gemm_split(const float* __restrict__ Af,
                const unsigned short* __restrict__ Ah,
                const unsigned short* __restrict__ Al, int lda,
                const float* __restrict__ B, int ldb,
                const float* __restrict__ bias,
                float* __restrict__ C,
                unsigned short* __restrict__ Ch,
                unsigned short* __restrict__ Cl, int ldc,
                int K)
{
    __shared__ short8v AsH[8][64];
    __shared__ short8v AsL[8][64];
    __shared__ short8v BsH[8][64];
    __shared__ short8v BsL[8][64];

    const int tid = threadIdx.x;
    const int l   = tid & 63;
    const int w   = tid >> 6;
    const int wm  = w & 1, wn = w >> 1;
    const int bm  = blockIdx.x * 128, bn = blockIdx.y * 128;

    const int sm    = tid >> 2;
    const int sk8   = (tid & 3) * 8;
    const int slane = (sm & 15) | ((sk8 >> 3) << 4);
    const int smf   = sm >> 4;

    f32x4 acc[4][4];
#pragma unroll
    for (int i = 0; i < 4; ++i)
#pragma unroll
        for (int j = 0; j < 4; ++j)
#pragma unroll
            for (int r = 0; r < 4; ++r) acc[i][j][r] = 0.f;

    for (int k0 = 0; k0 < K; k0 += 32) {
        if constexpr (A_SPLIT) {
            const size_t o0 = (size_t)(bm + sm) * lda + k0 + sk8;
            const size_t o1 = (size_t)(bm + sm + 64) * lda + k0 + sk8;
            AsH[smf][slane]     = *(const short8v*)(Ah + o0);
            AsL[smf][slane]     = *(const short8v*)(Al + o0);
            AsH[smf + 4][slane] = *(const short8v*)(Ah + o1);
            AsL[smf + 4][slane] = *(const short8v*)(Al + o1);
        } else {
            float fa[8], fb[8];
            const float* p0 = Af + (size_t)(bm + sm) * lda + k0 + sk8;
            const float* p1 = Af + (size_t)(bm + sm + 64) * lda + k0 + sk8;
            *(float4*)(fa)     = *(const float4*)(p0);
            *(float4*)(fa + 4) = *(const float4*)(p0 + 4);
            *(float4*)(fb)     = *(const float4*)(p1);
            *(float4*)(fb + 4) = *(const float4*)(p1 + 4);
            short8v hi, lo;
            split8(fa, hi, lo);
            AsH[smf][slane] = hi; AsL[smf][slane] = lo;
            split8(fb, hi, lo);
            AsH[smf + 4][slane] = hi; AsL[smf + 4][slane] = lo;
        }
        {
            float fa[8], fb[8];
            const float* p0 = B + (size_t)(bn + sm) * ldb + k0 + sk8;
            const float* p1 = B + (size_t)(bn + sm + 64) * ldb + k0 + sk8;
            *(float4*)(fa)     = *(const float4*)(p0);
            *(float4*)(fa + 4) = *(const float4*)(p0 + 4);
            *(float4*)(fb)     = *(const float4*)(p1);
            *(float4*)(fb + 4) = *(const float4*)(p1 + 4);
            short8v hi, lo;
            split8(fa, hi, lo);
            BsH[smf][slane] = hi; BsL[smf][slane] = lo;
            split8(fb, hi, lo);
            BsH[smf + 4][slane] = hi; BsL[smf + 4][slane] = lo;
        }
        __syncthreads();

        short8v a_h[4], a_l[4];
#pragma unroll
        for (int i = 0; i < 4; ++i) {
            a_h[i] = AsH[wm * 4 + i][l];
            a_l[i] = AsL[wm * 4 + i][l];
        }
#pragma unroll
        for (int j = 0; j < 4; ++j) {
            const short8v b_h = BsH[wn * 4 + j][l];
            const short8v b_l = BsL[wn * 4 + j][l];
#pragma unroll
            for (int i = 0; i < 4; ++i) {
                acc[i][j] = __builtin_amdgcn_mfma_f32_16x16x32_bf16(a_h[i], b_h, acc[i][j], 0, 0, 0);
                acc[i][j] = __builtin_amdgcn_mfma_f32_16x16x32_bf16(a_l[i], b_h, acc[i][j], 0, 0, 0);
                acc[i][j] = __builtin_amdgcn_mfma_f32_16x16x32_bf16(a_h[i], b_l, acc[i][j], 0, 0, 0);
            }
        }
        __syncthreads();
    }

    const int row0 = bm + wm * 64 + (l >> 4) * 4;
    const int col0 = bn + wn * 64 + (l & 15);
#pragma unroll
    for (int i = 0; i < 4; ++i) {
#pragma unroll
        for (int j = 0; j < 4; ++j) {
            const int col = col0 + j * 16;
            const float bs = bias[col];
#pragma unroll
            for (int r = 0; r < 4; ++r) {
                const int row = row0 + i * 16 + r;
                float v = acc[i][j][r] + bs;
                if (RELU) v = fmaxf(v, 0.f);
                if (OUT_SPLIT) {
                    unsigned short h = f2bf(v);
                    Ch[(size_t)row * ldc + col] = h;
                    Cl[(size_t)row * ldc + col] = f2bf(v - bf2f(h));
                } else {
                    C[(size_t)row * ldc + col] = v;
                }
            }
        }
    }
}

// --------------- W_hh -> split-bf16 B-fragment pre-pack --------------------
__global__ void pack_whh(const float* __restrict__ W, char* __restrict__ Wf) {
    int gid = blockIdx.x * blockDim.x + threadIdx.x;   // < 524288
    int l = gid & 63, fid = gid >> 6;
    int nt = fid & 1, kc = (fid >> 1) & 31, g = (fid >> 6) & 3, ng = fid >> 8;
    int n = g * 1024 + ng * 32 + nt * 16 + (l & 15);
    int k = kc * 32 + (l >> 4) * 8;
    const float* src = W + (size_t)n * 1024 + k;
    short8v hi, lo;
#pragma unroll
    for (int e = 0; e < 8; ++e) {
        float v = src[e];
        unsigned short hb = f2bf(v);
        hi[e] = (short)hb;
        lo[e] = (short)f2bf(v - bf2f(hb));
    }
    size_t off = (size_t)fid * 1024 + (size_t)l * 16;
    *(short8v*)(Wf + off) = hi;
    *(short8v*)(Wf + WF_LO_OFF + off) = lo;
}

__global__ void out_init(float* __restrict__ out, const float* __restrict__ b_cls) {
    int i = blockIdx.x * blockDim.x + threadIdx.x;
    if (i < 16384) out[i] = b_cls[i & 1];
}

// ------------------- phase C kernel 1: gate partials -----------------------
// WG (ng,kh,mh): rows mh*64..+64, gate-cols ng*32..+32 (all 4 gates, one per
// wave), K-slice kh*256..+256. Writes P[kh][g][row][col] f32.
__global__ __launch_bounds__(256)
void gate_partial(const char* __restrict__ Wf,
                  const char* __restrict__ hfrag,
                  float*      __restrict__ P,
                  int t)
{
    __shared__ short8v As[64][64];   // [ (hl*4+m)*8+kc ][ lane ]

    const int tid = threadIdx.x, bid = blockIdx.x;
    const int ng = bid & 31, kh = (bid >> 5) & 3, mh = bid >> 7;
    const int g  = tid >> 6,  l  = tid & 63;

    // stage h A-fragments (4 m-frags x 8 kc x hi/lo = 64 KB)
    const char* hbase = hfrag + ((t - 1) & 1) * HF_BUF;
#pragma unroll
    for (int it = 0; it < 16; ++it) {
        int u  = tid + it * 256;
        int hl = u >> 11, m = (u >> 9) & 3, kc = (u >> 6) & 7, ln = u & 63;
        As[u >> 6][ln] = *(const short8v*)(hbase + hl * HF_HL
                         + (size_t)(mh * 4 + m) * HF_MT
                         + (size_t)(kh * 8 + kc) * 1024 + ln * 16);
    }
    __syncthreads();

    f32x4 acc[4][2];
#pragma unroll
    for (int m = 0; m < 4; ++m)
#pragma unroll
        for (int nt = 0; nt < 2; ++nt)
#pragma unroll
            for (int r = 0; r < 4; ++r) acc[m][nt][r] = 0.f;

    const char* wb = Wf + ((size_t)(ng * 256 + g * 64 + kh * 16)) * 1024 + l * 16;
#pragma unroll
    for (int kc = 0; kc < 8; ++kc) {
        const char* w0 = wb + kc * 2048;
        const short8v bh0 = *(const short8v*)(w0);
        const short8v bh1 = *(const short8v*)(w0 + 1024);
        const short8v bl0 = *(const short8v*)(w0 + WF_LO_OFF);
        const short8v bl1 = *(const short8v*)(w0 + WF_LO_OFF + 1024);
#pragma unroll
        for (int m = 0; m < 4; ++m) {
            const short8v ah = As[m * 8 + kc][l];
            const short8v al = As[32 + m * 8 + kc][l];
            acc[m][0] = __builtin_amdgcn_mfma_f32_16x16x32_bf16(ah, bh0, acc[m][0], 0, 0, 0);
            acc[m][0] = __builtin_amdgcn_mfma_f32_16x16x32_bf16(al, bh0, acc[m][0], 0, 0, 0);
            acc[m][0] = __builtin_amdgcn_mfma_f32_16x16x32_bf16(ah, bl0, acc[m][0], 0, 0, 0);
            acc[m][1] = __builtin_amdgcn_mfma_f32_16x16x32_bf16(ah, bh1, acc[m][1], 0, 0, 0);
            acc[m][1] = __builtin_amdgcn_mfma_f32_16x16x32_bf16(al, bh1, acc[m][1], 0, 0, 0);
            acc[m][1] = __builtin_amdgcn_mfma_f32_16x16x32_bf16(ah, bl1, acc[m][1], 0, 0, 0);
        }
    }

    // write partials: D frag layout col=l&15, row=(l>>4)*4+r
    float* Pg = P + (size_t)(kh * 4 + g) * 131072 + ng * 32 + (l & 15);
    const int rbase = mh * 64 + (l >> 4) * 4;
#pragma unroll
    for (int m = 0; m < 4; ++m)
#pragma unroll
        for (int nt = 0; nt < 2; ++nt)
#pragma unroll
            for (int r = 0; r < 4; ++r)
                Pg[(size_t)(rbase + m * 16 + r) * 1024 + nt * 16] = acc[m][nt][r];
}

// --------------- phase C kernel 2: reduce + cell + classifier --------------
// 64 WGs: (mq = bid>>3, cq = bid&7). Thread (r = tid>>4, cw = tid&15) owns
// row mq*16+r, cols cq*128 + cw*8 .. +8.
__global__ __launch_bounds__(256)
void cell_cls(const float* __restrict__ P,
              const float* __restrict__ Gx,
              const float* __restrict__ b_hh,
              float*       __restrict__ c,
              char*        __restrict__ hfrag,
              const float* __restrict__ Wc,
              float*       __restrict__ out,
              int t)
{
    const int tid = threadIdx.x, bid = blockIdx.x;
    const int mq = bid >> 3, cq = bid & 7;
    const int r  = tid >> 4, cw = tid & 15;
    const int row  = mq * 16 + r;
    const int col0 = cq * 128 + cw * 8;

    float gate[4][8];
#pragma unroll
    for (int g = 0; g < 4; ++g) {
        const float* gx = Gx + ((size_t)row * 64 + t) * 4096 + g * 1024 + col0;
        const float* bh = b_hh + g * 1024 + col0;
        float4 v0 = *(const float4*)(gx), v1 = *(const float4*)(gx + 4);
        float4 b0 = *(const float4*)(bh), b1 = *(const float4*)(bh + 4);
        gate[g][0] = v0.x + b0.x; gate[g][1] = v0.y + b0.y;
        gate[g][2] = v0.z + b0.z; gate[g][3] = v0.w + b0.w;
        gate[g][4] = v1.x + b1.x; gate[g][5] = v1.y + b1.y;
        gate[g][6] = v1.z + b1.z; gate[g][7] = v1.w + b1.w;
    }
    if (t > 0) {
#pragma unroll
        for (int kh = 0; kh < 4; ++kh)
#pragma unroll
            for (int g = 0; g < 4; ++g) {
                const float* pp = P + (size_t)(kh * 4 + g) * 131072
                                + (size_t)row * 1024 + col0;
                float4 a = *(const float4*)(pp), b = *(const float4*)(pp + 4);
                gate[g][0] += a.x; gate[g][1] += a.y;
                gate[g][2] += a.z; gate[g][3] += a.w;
                gate[g][4] += b.x; gate[g][5] += b.y;
                gate[g][6] += b.z; gate[g][7] += b.w;
            }
    }

    float cold[8] = {0, 0, 0, 0, 0, 0, 0, 0};
    float* cp = c + (size_t)row * 1024 + col0;
    if (t > 0) {
        float4 a = *(const float4*)(cp), b = *(const float4*)(cp + 4);
        cold[0] = a.x; cold[1] = a.y; cold[2] = a.z; cold[3] = a.w;
        cold[4] = b.x; cold[5] = b.y; cold[6] = b.z; cold[7] = b.w;
    }

    float hv[8], cnew[8];
#pragma unroll
    for (int e = 0; e < 8; ++e) {
        float ig = 1.f / (1.f + __expf(-gate[0][e]));
        float fg = 1.f / (1.f + __expf(-gate[1][e]));
        float gg = tanhf(gate[2][e]);
        float og = 1.f / (1.f + __expf(-gate[3][e]));
        float cn = fg * cold[e] + ig * gg;
        cnew[e] = cn;
        hv[e] = og * tanhf(cn);
    }
    *(float4*)(cp)     = *(float4*)(cnew);
    *(float4*)(cp + 4) = *(float4*)(cnew + 4);

    // h hi/lo fragment write: this thread owns exactly one 16B lane slot
    short8v hi, lo;
    split8(hv, hi, lo);
    {
        const int kcf  = cq * 4 + (cw >> 2);
        const int lane = r | ((cw & 3) << 4);
        char* dst = hfrag + (t & 1) * HF_BUF + (size_t)mq * HF_MT
                  + (size_t)kcf * 1024 + lane * 16;
        *(short8v*)dst            = hi;
        *(short8v*)(dst + HF_HL)  = lo;
    }

    // classifier partial over this thread's 8 cols, reduce over cw (16 lanes)
    float s0 = 0.f, s1 = 0.f;
#pragma unroll
    for (int e = 0; e < 8; ++e) {
        s0 += hv[e] * Wc[col0 + e];
        s1 += hv[e] * Wc[1024 + col0 + e];
    }
#pragma unroll
    for (int off = 8; off > 0; off >>= 1) {
        s0 += __shfl_xor(s0, off);
        s1 += __shfl_xor(s1, off);
    }
    if (cw == 0) {
        float* o = out + ((size_t)row * 64 + t) * 2;
        atomicAdd(o,     s0);
        atomicAdd(o + 1, s1);
    }
}

// ---------------------------------------------------------------------------
extern "C" void kernel_launch(void* const* d_in, const int* in_sizes, int n_in,
                              void* d_out, int out_size, void* d_ws, size_t ws_size,
                              hipStream_t stream) {
    const float* x      = (const float*)d_in[0];
    const float* W_feat = (const float*)d_in[1];
    const float* b_feat = (const float*)d_in[2];
    const float* W_ih   = (const float*)d_in[3];
    const float* b_ih   = (const float*)d_in[4];
    const float* W_hh   = (const float*)d_in[5];
    const float* b_hh   = (const float*)d_in[6];
    const float* W_cls  = (const float*)d_in[7];
    const float* b_cls  = (const float*)d_in[8];
    float* out = (float*)d_out;

    char* ws = (char*)d_ws;
    unsigned short* Fh = (unsigned short*)ws;              // 16 MB
    unsigned short* Fl = (unsigned short*)(ws + 16777216); // 16 MB
    float* Gx    = (float*)(ws + 33554432);                // 128 MB
    char*  Wf    = ws;                                     // 16 MB (after B)
    char*  hfrag = ws + 16777216;                          // 1 MB
    float* c     = (float*)(ws + 17825792);                // 512 KB
    float* P     = (float*)(ws + P_OFF);                   // 8 MB

    // Phase A: Fh/Fl = split(relu(X @ W_feat^T + b_feat))  M=8192 N=1024 K=4096
    gemm_split<false, true, true>
        <<<dim3(64, 8), 256, 0, stream>>>(
            x, nullptr, nullptr, 4096, W_feat, 4096, b_feat,
            nullptr, Fh, Fl, 1024, 4096);

    // Phase B: Gx = F @ W_ih^T + b_ih   M=8192 N=4096 K=1024
    gemm_split<true, false, false>
        <<<dim3(64, 32), 256, 0, stream>>>(
            nullptr, Fh, Fl, 1024, W_ih, 1024, b_ih,
            Gx, nullptr, nullptr, 4096, 1024);

    // Pre-pack W_hh into split-bf16 fragments (overwrites Fh region)
    pack_whh<<<dim3(2048), dim3(256), 0, stream>>>(W_hh, Wf);

    out_init<<<dim3(64), dim3(256), 0, stream>>>(out, b_cls);

    // Phase C: 64 steps, two kernels each (K-split partials + cell)
    for (int t = 0; t < 64; ++t) {
        if (t > 0)
            gate_partial<<<dim3(256), 256, 0, stream>>>(Wf, hfrag, P, t);
        cell_cls<<<dim3(64), 256, 0, stream>>>(P, Gx, b_hh, c, hfrag,
                                               W_cls, out, t);
    }
}

// Round 8
// 1117.418 us; speedup vs baseline: 1.4914x; 1.4914x over previous
//
#include <hip/hip_runtime.h>
#include <math.h>

// ---------------------------------------------------------------------------
// DiscriminatorLSTM: B=128, T=64, FEAT=4096, FUSION=1024, H=1024, C=2
//
// Split-bf16 (hi/lo) MFMA: v = hi + lo, A*B ~= ah*bh + al*bh + ah*bl
//
// prep:    split_pair: W_feat (4,194,304 floats = 1,048,576 float4) -> Wfh/Wfl
// Phase A: Fh/Fl = split(relu(X @ W_feat^T + b_feat))
//          (A-side X f32 reg-split; B-side pre-split u16 staging)
// Phase B: Gx(f32) = F @ W_ih^T + b_ih   (A pre-split; B f32 reg-split)
// pack_whh (AFTER B, aliases Fh region): W_hh -> B-fragment pack
// Phase C: 64x lstm_step, 512 thr (8 waves = (gate g, K-half kh))
//
// ws layout (sizes verified):
//   [0,16M)    Fh  (8192x1024 u16 = 16 MB) | after B: Wf hi [0,8M) lo [8,16M)
//   [16,32M)   Fl  (16 MB)                 | after B: hfrag @16M (1MB), c @17M
//   [32,160M)  Gx f32 (8192x4096 = 128 MB) | BEFORE B: Wfh @32M (8MB), Wfl @40M
// ---------------------------------------------------------------------------

typedef __attribute__((ext_vector_type(8))) short short8v;   // 8 bf16
typedef __attribute__((ext_vector_type(4))) float f32x4;
typedef unsigned short u16;

#define WF_LO_OFF 8388608u
#define HF_BUF    524288
#define HF_HL     262144
#define HF_MT     32768

__device__ __forceinline__ u16 f2bf(float f) {   // RNE f32->bf16
    unsigned u = __builtin_bit_cast(unsigned, f);
    u = (u + 0x7fffu + ((u >> 16) & 1u)) >> 16;
    return (u16)u;
}
__device__ __forceinline__ float bf2f(u16 b) {
    unsigned u = ((unsigned)b) << 16;
    return __builtin_bit_cast(float, u);
}
__device__ __forceinline__ void split8(const float* f, short8v& hi, short8v& lo) {
#pragma unroll
    for (int e = 0; e < 8; ++e) {
        u16 h = f2bf(f[e]);
        hi[e] = (short)h;
        lo[e] = (short)f2bf(f[e] - bf2f(h));
    }
}

// ---------------- elementwise f32 -> (hi,lo) bf16 split --------------------
__global__ void split_pair(const float* __restrict__ src,
                           u16* __restrict__ dh, u16* __restrict__ dl, int n4) {
    int i = blockIdx.x * blockDim.x + threadIdx.x;
    if (i >= n4) return;
    float4 v = ((const float4*)src)[i];
    float f[4] = {v.x, v.y, v.z, v.w};
    u16 h[4], lo[4];
#pragma unroll
    for (int e = 0; e < 4; ++e) {
        h[e]  = f2bf(f[e]);
        lo[e] = f2bf(f[e] - bf2f(h[e]));
    }
    ((ushort4*)dh)[i] = make_ushort4(h[0], h[1], h[2], h[3]);
    ((ushort4*)dl)[i] = make_ushort4(lo[0], lo[1], lo[2], lo[3]);
}

// ------------------- split-bf16 MFMA GEMM  (C = A @ B^T) -------------------
template<bool A_PRESPLIT, bool B_PRESPLIT, bool RELU, bool OUT_SPLIT>
__global__ __launch_bounds__(256)
void gemm_mfma(const float* __restrict__ Af,
               const u16* __restrict__ Ah, const u16* __restrict__ Al, int lda,
               const float* __restrict__ Bf,
               const u16* __restrict__ Bh, const u16* __restrict__ Bl, int ldb,
               const float* __restrict__ bias,
               float* __restrict__ C, u16* __restrict__ Ch, u16* __restrict__ Cl,
               int ldc, int K)
{
    __shared__ short8v AsH[8][64];
    __shared__ short8v AsL[8][64];
    __shared__ short8v BsH[8][64];
    __shared__ short8v BsL[8][64];

    const int tid = threadIdx.x;
    const int l   = tid & 63;
    const int w   = tid >> 6;
    const int wm  = w & 1, wn = w >> 1;
    const int bm  = blockIdx.x * 128, bn = blockIdx.y * 128;

    const int sm    = tid >> 2;
    const int sk8   = (tid & 3) * 8;
    const int slane = (sm & 15) | ((sk8 >> 3) << 4);
    const int smf   = sm >> 4;

    f32x4 acc[4][4];
#pragma unroll
    for (int i = 0; i < 4; ++i)
#pragma unroll
        for (int j = 0; j < 4; ++j)
#pragma unroll
            for (int r = 0; r < 4; ++r) acc[i][j][r] = 0.f;

    for (int k0 = 0; k0 < K; k0 += 32) {
        if constexpr (A_PRESPLIT) {
            const size_t o0 = (size_t)(bm + sm) * lda + k0 + sk8;
            const size_t o1 = (size_t)(bm + sm + 64) * lda + k0 + sk8;
            AsH[smf][slane]     = *(const short8v*)(Ah + o0);
            AsL[smf][slane]     = *(const short8v*)(Al + o0);
            AsH[smf + 4][slane] = *(const short8v*)(Ah + o1);
            AsL[smf + 4][slane] = *(const short8v*)(Al + o1);
        } else {
            float fa[8], fb[8];
            const float* p0 = Af + (size_t)(bm + sm) * lda + k0 + sk8;
            const float* p1 = Af + (size_t)(bm + sm + 64) * lda + k0 + sk8;
            *(float4*)(fa)     = *(const float4*)(p0);
            *(float4*)(fa + 4) = *(const float4*)(p0 + 4);
            *(float4*)(fb)     = *(const float4*)(p1);
            *(float4*)(fb + 4) = *(const float4*)(p1 + 4);
            short8v hi, lo;
            split8(fa, hi, lo);
            AsH[smf][slane] = hi; AsL[smf][slane] = lo;
            split8(fb, hi, lo);
            AsH[smf + 4][slane] = hi; AsL[smf + 4][slane] = lo;
        }
        if constexpr (B_PRESPLIT) {
            const size_t o0 = (size_t)(bn + sm) * ldb + k0 + sk8;
            const size_t o1 = (size_t)(bn + sm + 64) * ldb + k0 + sk8;
            BsH[smf][slane]     = *(const short8v*)(Bh + o0);
            BsL[smf][slane]     = *(const short8v*)(Bl + o0);
            BsH[smf + 4][slane] = *(const short8v*)(Bh + o1);
            BsL[smf + 4][slane] = *(const short8v*)(Bl + o1);
        } else {
            float fa[8], fb[8];
            const float* p0 = Bf + (size_t)(bn + sm) * ldb + k0 + sk8;
            const float* p1 = Bf + (size_t)(bn + sm + 64) * ldb + k0 + sk8;
            *(float4*)(fa)     = *(const float4*)(p0);
            *(float4*)(fa + 4) = *(const float4*)(p0 + 4);
            *(float4*)(fb)     = *(const float4*)(p1);
            *(float4*)(fb + 4) = *(const float4*)(p1 + 4);
            short8v hi, lo;
            split8(fa, hi, lo);
            BsH[smf][slane] = hi; BsL[smf][slane] = lo;
            split8(fb, hi, lo);
            BsH[smf + 4][slane] = hi; BsL[smf + 4][slane] = lo;
        }
        __syncthreads();

        short8v a_h[4], a_l[4];
#pragma unroll
        for (int i = 0; i < 4; ++i) {
            a_h[i] = AsH[wm * 4 + i][l];
            a_l[i] = AsL[wm * 4 + i][l];
        }
#pragma unroll
        for (int j = 0; j < 4; ++j) {
            const short8v b_h = BsH[wn * 4 + j][l];
            const short8v b_l = BsL[wn * 4 + j][l];
#pragma unroll
            for (int i = 0; i < 4; ++i) {
                acc[i][j] = __builtin_amdgcn_mfma_f32_16x16x32_bf16(a_h[i], b_h, acc[i][j], 0, 0, 0);
                acc[i][j] = __builtin_amdgcn_mfma_f32_16x16x32_bf16(a_l[i], b_h, acc[i][j], 0, 0, 0);
                acc[i][j] = __builtin_amdgcn_mfma_f32_16x16x32_bf16(a_h[i], b_l, acc[i][j], 0, 0, 0);
            }
        }
        __syncthreads();
    }

    const int row0 = bm + wm * 64 + (l >> 4) * 4;
    const int col0 = bn + wn * 64 + (l & 15);
#pragma unroll
    for (int i = 0; i < 4; ++i) {
#pragma unroll
        for (int j = 0; j < 4; ++j) {
            const int col = col0 + j * 16;
            const float bs = bias[col];
#pragma unroll
            for (int r = 0; r < 4; ++r) {
                const int row = row0 + i * 16 + r;
                float v = acc[i][j][r] + bs;
                if (RELU) v = fmaxf(v, 0.f);
                if (OUT_SPLIT) {
                    u16 h = f2bf(v);
                    Ch[(size_t)row * ldc + col] = h;
                    Cl[(size_t)row * ldc + col] = f2bf(v - bf2f(h));
                } else {
                    C[(size_t)row * ldc + col] = v;
                }
            }
        }
    }
}

// --------------- W_hh -> split-bf16 B-fragment pre-pack --------------------
__global__ void pack_whh(const float* __restrict__ W, char* __restrict__ Wf) {
    int gid = blockIdx.x * blockDim.x + threadIdx.x;   // < 524288
    int l = gid & 63, fid = gid >> 6;
    int nt = fid & 1, kc = (fid >> 1) & 31, g = (fid >> 6) & 3, ng = fid >> 8;
    int n = g * 1024 + ng * 32 + nt * 16 + (l & 15);
    int k = kc * 32 + (l >> 4) * 8;
    const float* src = W + (size_t)n * 1024 + k;
    short8v hi, lo;
#pragma unroll
    for (int e = 0; e < 8; ++e) {
        float v = src[e];
        u16 hb = f2bf(v);
        hi[e] = (short)hb;
        lo[e] = (short)f2bf(v - bf2f(hb));
    }
    size_t off = (size_t)fid * 1024 + (size_t)l * 16;
    *(short8v*)(Wf + off) = hi;
    *(short8v*)(Wf + WF_LO_OFF + off) = lo;
}

__global__ void out_init(float* __restrict__ out, const float* __restrict__ b_cls) {
    int i = blockIdx.x * blockDim.x + threadIdx.x;
    if (i < 16384) out[i] = b_cls[i & 1];
}

// --------------------------- fused LSTM step -------------------------------
__global__ __launch_bounds__(512)
void lstm_step(const float* __restrict__ Gx,
               const float* __restrict__ b_hh,
               const char*  __restrict__ Wf,
               char*        __restrict__ hfrag,
               float*       __restrict__ c,
               const float* __restrict__ Wc,
               float*       __restrict__ out,
               int t)
{
    __shared__ short8v Hs[64][64];            // 64 KB: [hl*32+kc][lane]
    __shared__ float gates_s[2][4][16][33];   // [kh][g][row][col]
    __shared__ float h_s[16][33];
    __shared__ float Wc_s[2][32];

    const int tid = threadIdx.x, bid = blockIdx.x;
    const int w = tid >> 6, l = tid & 63;
    const int g = w & 3, kh = w >> 2;
    const int slot = bid >> 3;
    const int m_tile = slot & 7;
    const int ng = (bid & 7) * 4 + (slot >> 3);   // XCD-grouped col-chunk

    if (tid < 64) Wc_s[tid >> 5][tid & 31] =
        Wc[(size_t)(tid >> 5) * 1024 + ng * 32 + (tid & 31)];

    const int lhi = l >> 4;
    const int llo = l & 15;

    f32x4 aA0, aB0, aA1, aB1;
#pragma unroll
    for (int r = 0; r < 4; ++r) { aA0[r] = 0.f; aB0[r] = 0.f; aA1[r] = 0.f; aB1[r] = 0.f; }

    if (t > 0) {
        const char* hbase = hfrag + ((t - 1) & 1) * HF_BUF + (size_t)m_tile * HF_MT;
#pragma unroll
        for (int i = 0; i < 8; ++i) {
            const int s = w * 8 + i;                 // hl = s>>5, kc = s&31
            Hs[s][l] = *(const short8v*)(hbase + (size_t)(s >> 5) * HF_HL
                        + (size_t)(s & 31) * 1024 + (size_t)l * 16);
        }
        __syncthreads();

        const char* wb = Wf + (size_t)(ng * 4 + g) * 65536
                       + (size_t)kh * 32768 + (size_t)l * 16;
#pragma unroll 4
        for (int kcl = 0; kcl < 16; ++kcl) {
            const char* w0 = wb + kcl * 2048;
            const short8v bh0 = *(const short8v*)(w0);
            const short8v bh1 = *(const short8v*)(w0 + 1024);
            const short8v bl0 = *(const short8v*)(w0 + WF_LO_OFF);
            const short8v bl1 = *(const short8v*)(w0 + WF_LO_OFF + 1024);
            const int kc = kh * 16 + kcl;
            const short8v ah = Hs[kc][l];
            const short8v al = Hs[32 + kc][l];
            aA0 = __builtin_amdgcn_mfma_f32_16x16x32_bf16(ah, bh0, aA0, 0, 0, 0);
            aB0 = __builtin_amdgcn_mfma_f32_16x16x32_bf16(al, bh0, aB0, 0, 0, 0);
            aB0 = __builtin_amdgcn_mfma_f32_16x16x32_bf16(ah, bl0, aB0, 0, 0, 0);
            aA1 = __builtin_amdgcn_mfma_f32_16x16x32_bf16(ah, bh1, aA1, 0, 0, 0);
            aB1 = __builtin_amdgcn_mfma_f32_16x16x32_bf16(al, bh1, aB1, 0, 0, 0);
            aB1 = __builtin_amdgcn_mfma_f32_16x16x32_bf16(ah, bl1, aB1, 0, 0, 0);
        }
    }

#pragma unroll
    for (int r = 0; r < 4; ++r) {
        gates_s[kh][g][lhi * 4 + r][llo]      = aA0[r] + aB0[r];
        gates_s[kh][g][lhi * 4 + r][16 + llo] = aA1[r] + aB1[r];
    }
    __syncthreads();

    {
        const int r  = tid >> 5;
        const int cc = tid & 31;
        const int row = m_tile * 16 + r;
        float gate[4];
#pragma unroll
        for (int gg = 0; gg < 4; ++gg) {
            const size_t gidx = ((size_t)row * 64 + t) * 4096
                              + (size_t)gg * 1024 + ng * 32 + cc;
            gate[gg] = gates_s[0][gg][r][cc] + gates_s[1][gg][r][cc]
                     + Gx[gidx] + b_hh[gg * 1024 + ng * 32 + cc];
        }
        float ig = 1.f / (1.f + __expf(-gate[0]));
        float fg = 1.f / (1.f + __expf(-gate[1]));
        float gg = tanhf(gate[2]);
        float og = 1.f / (1.f + __expf(-gate[3]));
        const size_t cidx = (size_t)row * 1024 + ng * 32 + cc;
        float cp = (t > 0) ? c[cidx] : 0.f;
        float cn = fg * cp + ig * gg;
        float hn = og * tanhf(cn);
        c[cidx] = cn;
        h_s[r][cc] = hn;
    }
    __syncthreads();

    if (w < 2) {
        short8v v;
#pragma unroll
        for (int e = 0; e < 8; ++e) {
            float hv = h_s[llo][lhi * 8 + e];
            u16 hb_ = f2bf(hv);
            v[e] = (short)(w == 0 ? hb_ : f2bf(hv - bf2f(hb_)));
        }
        char* dst = hfrag + (t & 1) * HF_BUF + (size_t)w * HF_HL
                  + (size_t)m_tile * HF_MT + (size_t)ng * 1024 + (size_t)l * 16;
        *(short8v*)dst = v;
    } else if (w == 2 && l < 32) {
        const int m = l & 15, cls = l >> 4;
        float s = 0.f;
#pragma unroll
        for (int cc = 0; cc < 32; ++cc) s += h_s[m][cc] * Wc_s[cls][cc];
        atomicAdd(out + ((size_t)(m_tile * 16 + m) * 64 + t) * 2 + cls, s);
    }
}

// ---------------------------------------------------------------------------
extern "C" void kernel_launch(void* const* d_in, const int* in_sizes, int n_in,
                              void* d_out, int out_size, void* d_ws, size_t ws_size,
                              hipStream_t stream) {
    const float* x      = (const float*)d_in[0];
    const float* W_feat = (const float*)d_in[1];
    const float* b_feat = (const float*)d_in[2];
    const float* W_ih   = (const float*)d_in[3];
    const float* b_ih   = (const float*)d_in[4];
    const float* W_hh   = (const float*)d_in[5];
    const float* b_hh   = (const float*)d_in[6];
    const float* W_cls  = (const float*)d_in[7];
    const float* b_cls  = (const float*)d_in[8];
    float* out = (float*)d_out;

    char* ws = (char*)d_ws;
    u16*  Fh  = (u16*)ws;                      // [0,16M)  8192x1024 u16
    u16*  Fl  = (u16*)(ws + 16777216);         // [16,32M)
    float* Gx = (float*)(ws + 33554432);       // [32,160M) 8192x4096 f32
    u16*  Wfh = (u16*)(ws + 33554432);         // [32,40M)  1024x4096 u16, dead at B
    u16*  Wfl = (u16*)(ws + 41943040);         // [40,48M)  dead at B
    char* Wf    = ws;                          // [0,16M)  after pack (post-B)
    char* hfrag = ws + 16777216;               // [16,17M) post-B
    float* c    = (float*)(ws + 17825792);     // [17,17.5M) post-B

    // prep: W_feat = 1024x4096 = 4,194,304 floats = 1,048,576 float4 chunks
    split_pair<<<dim3(4096), dim3(256), 0, stream>>>(W_feat, Wfh, Wfl, 1048576);
    out_init<<<dim3(64), dim3(256), 0, stream>>>(out, b_cls);

    // Phase A: Fh/Fl = split(relu(X @ W_feat^T + b_feat))  M=8192 N=1024 K=4096
    gemm_mfma<false, true, true, true>
        <<<dim3(64, 8), 256, 0, stream>>>(
            x, nullptr, nullptr, 4096,
            nullptr, Wfh, Wfl, 4096, b_feat,
            nullptr, Fh, Fl, 1024, 4096);

    // Phase B: Gx = F @ W_ih^T + b_ih   M=8192 N=4096 K=1024  (round-3 config)
    gemm_mfma<true, false, false, false>
        <<<dim3(64, 32), 256, 0, stream>>>(
            nullptr, Fh, Fl, 1024,
            W_ih, nullptr, nullptr, 1024, b_ih,
            Gx, nullptr, nullptr, 4096, 1024);

    // pack W_hh fragments AFTER phase B (aliases dead Fh region)
    pack_whh<<<dim3(2048), dim3(256), 0, stream>>>(W_hh, Wf);

    // Phase C: 64 fused recurrent steps
    for (int t = 0; t < 64; ++t) {
        lstm_step<<<dim3(256), dim3(512), 0, stream>>>(
            Gx, b_hh, Wf, hfrag, c, W_cls, out, t);
    }
}

// Round 9
// 1063.539 us; speedup vs baseline: 1.5669x; 1.0507x over previous
//
#include <hip/hip_runtime.h>
#include <math.h>

// ---------------------------------------------------------------------------
// DiscriminatorLSTM: B=128, T=64, FEAT=4096, FUSION=1024, H=1024, C=2
//
// Split-bf16 (hi/lo) MFMA: v = hi + lo, A*B ~= ah*bh + al*bh + ah*bl
//
// prep:    split_pair: W_feat (1024x4096 = 1,048,576 float4) -> Wfh/Wfl
// Phase A: Fh/Fl = split(relu(X @ W_feat^T + b_feat))
// Phase B: Gx(f32) = F @ W_ih^T + b_ih
// pack_whh2 (AFTER B, aliases Fh region): W_hh -> 16-col B-fragment pack
// Phase C: 64x lstm_step, 512 thr, WG = (mh 0..3, ngrp 0..63):
//          32 rows x 16 cols/gate tile -> 384 KB/CU/step L2 traffic
//
// GEMM LDS swizzle: fragment position p = (row ^ (koct<<1)) | (koct<<4)
// kills the 4-way staging-write bank conflict (5.03e7/dispatch in r8).
//
// ws layout (sizes verified):
//   [0,16M)    Fh (8192x1024 u16) | after B: Wf2 hi [0,8M) lo [8,16M)
//   [16,32M)   Fl                 | after B: hfrag @16M (1MB), c @17M (512K)
//   [32,160M)  Gx f32 (128 MB)    | BEFORE B: Wfh @32M (8MB), Wfl @40M (8MB)
// ---------------------------------------------------------------------------

typedef __attribute__((ext_vector_type(8))) short short8v;   // 8 bf16
typedef __attribute__((ext_vector_type(4))) float f32x4;
typedef unsigned short u16;

#define WF_LO_OFF 8388608u
#define HF_BUF    524288
#define HF_HL     262144
#define HF_MT     32768

__device__ __forceinline__ u16 f2bf(float f) {   // RNE f32->bf16
    unsigned u = __builtin_bit_cast(unsigned, f);
    u = (u + 0x7fffu + ((u >> 16) & 1u)) >> 16;
    return (u16)u;
}
__device__ __forceinline__ float bf2f(u16 b) {
    unsigned u = ((unsigned)b) << 16;
    return __builtin_bit_cast(float, u);
}
__device__ __forceinline__ void split8(const float* f, short8v& hi, short8v& lo) {
#pragma unroll
    for (int e = 0; e < 8; ++e) {
        u16 h = f2bf(f[e]);
        hi[e] = (short)h;
        lo[e] = (short)f2bf(f[e] - bf2f(h));
    }
}

// ---------------- elementwise f32 -> (hi,lo) bf16 split --------------------
__global__ void split_pair(const float* __restrict__ src,
                           u16* __restrict__ dh, u16* __restrict__ dl, int n4) {
    int i = blockIdx.x * blockDim.x + threadIdx.x;
    if (i >= n4) return;
    float4 v = ((const float4*)src)[i];
    float f[4] = {v.x, v.y, v.z, v.w};
    u16 h[4], lo[4];
#pragma unroll
    for (int e = 0; e < 4; ++e) {
        h[e]  = f2bf(f[e]);
        lo[e] = f2bf(f[e] - bf2f(h[e]));
    }
    ((ushort4*)dh)[i] = make_ushort4(h[0], h[1], h[2], h[3]);
    ((ushort4*)dl)[i] = make_ushort4(lo[0], lo[1], lo[2], lo[3]);
}

// ------------------- split-bf16 MFMA GEMM  (C = A @ B^T) -------------------
// Fragment LDS position swizzle: p = (row ^ (koct<<1)) | (koct<<4).
template<bool A_PRESPLIT, bool B_PRESPLIT, bool RELU, bool OUT_SPLIT>
__global__ __launch_bounds__(256)
void gemm_mfma(const float* __restrict__ Af,
               const u16* __restrict__ Ah, const u16* __restrict__ Al, int lda,
               const float* __restrict__ Bf,
               const u16* __restrict__ Bh, const u16* __restrict__ Bl, int ldb,
               const float* __restrict__ bias,
               float* __restrict__ C, u16* __restrict__ Ch, u16* __restrict__ Cl,
               int ldc, int K)
{
    __shared__ short8v AsH[8][64];
    __shared__ short8v AsL[8][64];
    __shared__ short8v BsH[8][64];
    __shared__ short8v BsL[8][64];

    const int tid = threadIdx.x;
    const int l   = tid & 63;
    const int w   = tid >> 6;
    const int wm  = w & 1, wn = w >> 1;
    const int bm  = blockIdx.x * 128, bn = blockIdx.y * 128;

    const int sm    = tid >> 2;
    const int sk8   = (tid & 3) * 8;
    const int koct_s = sk8 >> 3;
    const int slane = ((sm & 15) ^ (koct_s << 1)) | (koct_s << 4);  // swizzled
    const int smf   = sm >> 4;
    const int lsw   = ((l & 15) ^ ((l >> 4) << 1)) | (l & 48);      // read side

    f32x4 acc[4][4];
#pragma unroll
    for (int i = 0; i < 4; ++i)
#pragma unroll
        for (int j = 0; j < 4; ++j)
#pragma unroll
            for (int r = 0; r < 4; ++r) acc[i][j][r] = 0.f;

    for (int k0 = 0; k0 < K; k0 += 32) {
        if constexpr (A_PRESPLIT) {
            const size_t o0 = (size_t)(bm + sm) * lda + k0 + sk8;
            const size_t o1 = (size_t)(bm + sm + 64) * lda + k0 + sk8;
            AsH[smf][slane]     = *(const short8v*)(Ah + o0);
            AsL[smf][slane]     = *(const short8v*)(Al + o0);
            AsH[smf + 4][slane] = *(const short8v*)(Ah + o1);
            AsL[smf + 4][slane] = *(const short8v*)(Al + o1);
        } else {
            float fa[8], fb[8];
            const float* p0 = Af + (size_t)(bm + sm) * lda + k0 + sk8;
            const float* p1 = Af + (size_t)(bm + sm + 64) * lda + k0 + sk8;
            *(float4*)(fa)     = *(const float4*)(p0);
            *(float4*)(fa + 4) = *(const float4*)(p0 + 4);
            *(float4*)(fb)     = *(const float4*)(p1);
            *(float4*)(fb + 4) = *(const float4*)(p1 + 4);
            short8v hi, lo;
            split8(fa, hi, lo);
            AsH[smf][slane] = hi; AsL[smf][slane] = lo;
            split8(fb, hi, lo);
            AsH[smf + 4][slane] = hi; AsL[smf + 4][slane] = lo;
        }
        if constexpr (B_PRESPLIT) {
            const size_t o0 = (size_t)(bn + sm) * ldb + k0 + sk8;
            const size_t o1 = (size_t)(bn + sm + 64) * ldb + k0 + sk8;
            BsH[smf][slane]     = *(const short8v*)(Bh + o0);
            BsL[smf][slane]     = *(const short8v*)(Bl + o0);
            BsH[smf + 4][slane] = *(const short8v*)(Bh + o1);
            BsL[smf + 4][slane] = *(const short8v*)(Bl + o1);
        } else {
            float fa[8], fb[8];
            const float* p0 = Bf + (size_t)(bn + sm) * ldb + k0 + sk8;
            const float* p1 = Bf + (size_t)(bn + sm + 64) * ldb + k0 + sk8;
            *(float4*)(fa)     = *(const float4*)(p0);
            *(float4*)(fa + 4) = *(const float4*)(p0 + 4);
            *(float4*)(fb)     = *(const float4*)(p1);
            *(float4*)(fb + 4) = *(const float4*)(p1 + 4);
            short8v hi, lo;
            split8(fa, hi, lo);
            BsH[smf][slane] = hi; BsL[smf][slane] = lo;
            split8(fb, hi, lo);
            BsH[smf + 4][slane] = hi; BsL[smf + 4][slane] = lo;
        }
        __syncthreads();

        short8v a_h[4], a_l[4];
#pragma unroll
        for (int i = 0; i < 4; ++i) {
            a_h[i] = AsH[wm * 4 + i][lsw];
            a_l[i] = AsL[wm * 4 + i][lsw];
        }
#pragma unroll
        for (int j = 0; j < 4; ++j) {
            const short8v b_h = BsH[wn * 4 + j][lsw];
            const short8v b_l = BsL[wn * 4 + j][lsw];
#pragma unroll
            for (int i = 0; i < 4; ++i) {
                acc[i][j] = __builtin_amdgcn_mfma_f32_16x16x32_bf16(a_h[i], b_h, acc[i][j], 0, 0, 0);
                acc[i][j] = __builtin_amdgcn_mfma_f32_16x16x32_bf16(a_l[i], b_h, acc[i][j], 0, 0, 0);
                acc[i][j] = __builtin_amdgcn_mfma_f32_16x16x32_bf16(a_h[i], b_l, acc[i][j], 0, 0, 0);
            }
        }
        __syncthreads();
    }

    const int row0 = bm + wm * 64 + (l >> 4) * 4;
    const int col0 = bn + wn * 64 + (l & 15);
#pragma unroll
    for (int i = 0; i < 4; ++i) {
#pragma unroll
        for (int j = 0; j < 4; ++j) {
            const int col = col0 + j * 16;
            const float bs = bias[col];
#pragma unroll
            for (int r = 0; r < 4; ++r) {
                const int row = row0 + i * 16 + r;
                float v = acc[i][j][r] + bs;
                if (RELU) v = fmaxf(v, 0.f);
                if (OUT_SPLIT) {
                    u16 h = f2bf(v);
                    Ch[(size_t)row * ldc + col] = h;
                    Cl[(size_t)row * ldc + col] = f2bf(v - bf2f(h));
                } else {
                    C[(size_t)row * ldc + col] = v;
                }
            }
        }
    }
}

// ----------- W_hh -> 16-col split-bf16 B-fragment pre-pack -----------------
// fid = (g<<11)|(ngrp<<5)|(kh<<4)|kcl ; lane l: n = g*1024+ngrp*16+(l&15),
// k = kh*512 + kcl*32 + (l>>4)*8
__global__ void pack_whh2(const float* __restrict__ W, char* __restrict__ Wf) {
    int gid = blockIdx.x * blockDim.x + threadIdx.x;   // < 524288
    int l = gid & 63, fid = gid >> 6;                  // fid < 8192
    int kcl = fid & 15, kh = (fid >> 4) & 1, ngrp = (fid >> 5) & 63, g = fid >> 11;
    int n = g * 1024 + ngrp * 16 + (l & 15);
    int k = kh * 512 + kcl * 32 + (l >> 4) * 8;
    const float* src = W + (size_t)n * 1024 + k;
    short8v hi, lo;
#pragma unroll
    for (int e = 0; e < 8; ++e) {
        float v = src[e];
        u16 hb = f2bf(v);
        hi[e] = (short)hb;
        lo[e] = (short)f2bf(v - bf2f(hb));
    }
    size_t off = (size_t)fid * 1024 + (size_t)l * 16;
    *(short8v*)(Wf + off) = hi;
    *(short8v*)(Wf + WF_LO_OFF + off) = lo;
}

__global__ void out_init(float* __restrict__ out, const float* __restrict__ b_cls) {
    int i = blockIdx.x * blockDim.x + threadIdx.x;
    if (i < 16384) out[i] = b_cls[i & 1];
}

// --------------------------- fused LSTM step -------------------------------
// 256 WGs x 512 thr. WG (mh = bid>>6, ngrp = bid&63): rows mh*32..+32,
// per-gate cols ngrp*16..+16. Wave w: gate g=w&3, K-half kh=w>>2;
// each wave does 2 m-frags x 1 n-frag x 16 ksteps x 3 products = 96 MFMA.
__global__ __launch_bounds__(512)
void lstm_step(const float* __restrict__ Gx,
               const float* __restrict__ b_hh,
               const char*  __restrict__ Wf,
               char*        __restrict__ hfrag,
               float*       __restrict__ c,
               const float* __restrict__ Wc,
               float*       __restrict__ out,
               int t)
{
    __shared__ short8v Hs[128][64];          // 128 KB: s = (hl*2+mf)*32 + kc
    __shared__ float gates_s[2][4][32][16];  // 16 KB: [kh][g][row32][col16]
    __shared__ float h_s[32][16];            // 2 KB
    __shared__ float Wc_s[2][16];

    const int tid = threadIdx.x, bid = blockIdx.x;
    const int w = tid >> 6, l = tid & 63;
    const int g = w & 3, kh = w >> 2;
    const int ngrp = bid & 63, mh = bid >> 6;

    if (tid < 32) Wc_s[tid >> 4][tid & 15] =
        Wc[(size_t)(tid >> 4) * 1024 + ngrp * 16 + (tid & 15)];

    const int lhi = l >> 4;
    const int llo = l & 15;

    f32x4 aA0, aB0, aA1, aB1;
#pragma unroll
    for (int r = 0; r < 4; ++r) { aA0[r] = 0.f; aB0[r] = 0.f; aA1[r] = 0.f; aB1[r] = 0.f; }

    if (t > 0) {
        // stage h hi/lo fragments for m_tiles {2mh, 2mh+1}: 128 slots x 1 KB
        const char* hbase = hfrag + ((t - 1) & 1) * HF_BUF;
#pragma unroll
        for (int it = 0; it < 16; ++it) {
            const int u  = tid + it * 512;      // 0..8191
            const int s  = u >> 6;              // slot: hl = s>>6, mf = (s>>5)&1, kc = s&31
            const int ln = u & 63;
            Hs[s][ln] = *(const short8v*)(hbase
                        + (size_t)(s >> 6) * HF_HL
                        + (size_t)(2 * mh + ((s >> 5) & 1)) * HF_MT
                        + (size_t)(s & 31) * 1024 + (size_t)ln * 16);
        }
        __syncthreads();

        const char* wb = Wf + (size_t)((g * 64 + ngrp) * 2 + kh) * 16384 + (size_t)l * 16;
#pragma unroll 4
        for (int kcl = 0; kcl < 16; ++kcl) {
            const char* w0 = wb + kcl * 1024;
            const short8v bh = *(const short8v*)(w0);
            const short8v bl = *(const short8v*)(w0 + WF_LO_OFF);
            const int kc = kh * 16 + kcl;
            const short8v ah0 = Hs[kc][l];         // hl0 mf0
            const short8v ah1 = Hs[32 + kc][l];    // hl0 mf1
            const short8v al0 = Hs[64 + kc][l];    // hl1 mf0
            const short8v al1 = Hs[96 + kc][l];    // hl1 mf1
            aA0 = __builtin_amdgcn_mfma_f32_16x16x32_bf16(ah0, bh, aA0, 0, 0, 0);
            aB0 = __builtin_amdgcn_mfma_f32_16x16x32_bf16(al0, bh, aB0, 0, 0, 0);
            aB0 = __builtin_amdgcn_mfma_f32_16x16x32_bf16(ah0, bl, aB0, 0, 0, 0);
            aA1 = __builtin_amdgcn_mfma_f32_16x16x32_bf16(ah1, bh, aA1, 0, 0, 0);
            aB1 = __builtin_amdgcn_mfma_f32_16x16x32_bf16(al1, bh, aB1, 0, 0, 0);
            aB1 = __builtin_amdgcn_mfma_f32_16x16x32_bf16(ah1, bl, aB1, 0, 0, 0);
        }
    }

    // partial gate tiles -> LDS (zeros at t==0); D: col=l&15, row=lhi*4+r
#pragma unroll
    for (int r = 0; r < 4; ++r) {
        gates_s[kh][g][lhi * 4 + r][llo]      = aA0[r] + aB0[r];
        gates_s[kh][g][16 + lhi * 4 + r][llo] = aA1[r] + aB1[r];
    }
    __syncthreads();

    // LSTM cell: 512 threads = 32 rows x 16 cols, one element each
    {
        const int r  = tid >> 4;
        const int cw = tid & 15;
        const int row = mh * 32 + r;
        const int col = ngrp * 16 + cw;
        float gate[4];
#pragma unroll
        for (int gg = 0; gg < 4; ++gg) {
            const size_t gidx = ((size_t)row * 64 + t) * 4096
                              + (size_t)gg * 1024 + col;
            gate[gg] = gates_s[0][gg][r][cw] + gates_s[1][gg][r][cw]
                     + Gx[gidx] + b_hh[gg * 1024 + col];
        }
        float ig = 1.f / (1.f + __expf(-gate[0]));
        float fg = 1.f / (1.f + __expf(-gate[1]));
        float gg = tanhf(gate[2]);
        float og = 1.f / (1.f + __expf(-gate[3]));
        const size_t cidx = (size_t)row * 1024 + col;
        float cp = (t > 0) ? c[cidx] : 0.f;
        float cn = fg * cp + ig * gg;
        float hn = og * tanhf(cn);
        c[cidx] = cn;
        h_s[r][cw] = hn;

        // classifier partial: reduce over 16 cols (cw), then atomicAdd
        float s0 = hn * Wc_s[0][cw];
        float s1 = hn * Wc_s[1][cw];
#pragma unroll
        for (int off = 8; off > 0; off >>= 1) {
            s0 += __shfl_xor(s0, off);
            s1 += __shfl_xor(s1, off);
        }
        if (cw == 0) {
            float* o = out + ((size_t)row * 64 + t) * 2;
            atomicAdd(o,     s0);
            atomicAdd(o + 1, s1);
        }
    }
    __syncthreads();

    // h-fragment write: this WG owns kc = ngrp>>1, koct pair (ngrp&1)*2..+1,
    // m_tiles 2mh..2mh+1, hi/lo.  128 threads x 16B chunks.
    if (tid < 128) {
        const int idx16  = tid & 15;
        const int koct_h = (tid >> 4) & 1;
        const int mt_l   = (tid >> 5) & 1;
        const int hl     = tid >> 6;
        const int lane   = idx16 | (((ngrp & 1) * 2 + koct_h) << 4);
        short8v v;
#pragma unroll
        for (int e = 0; e < 8; ++e) {
            float hv = h_s[mt_l * 16 + idx16][koct_h * 8 + e];
            u16 hb_ = f2bf(hv);
            v[e] = (short)(hl == 0 ? hb_ : f2bf(hv - bf2f(hb_)));
        }
        char* dst = hfrag + (t & 1) * HF_BUF + (size_t)hl * HF_HL
                  + (size_t)(2 * mh + mt_l) * HF_MT
                  + (size_t)(ngrp >> 1) * 1024 + (size_t)lane * 16;
        *(short8v*)dst = v;
    }
}

// ---------------------------------------------------------------------------
extern "C" void kernel_launch(void* const* d_in, const int* in_sizes, int n_in,
                              void* d_out, int out_size, void* d_ws, size_t ws_size,
                              hipStream_t stream) {
    const float* x      = (const float*)d_in[0];
    const float* W_feat = (const float*)d_in[1];
    const float* b_feat = (const float*)d_in[2];
    const float* W_ih   = (const float*)d_in[3];
    const float* b_ih   = (const float*)d_in[4];
    const float* W_hh   = (const float*)d_in[5];
    const float* b_hh   = (const float*)d_in[6];
    const float* W_cls  = (const float*)d_in[7];
    const float* b_cls  = (const float*)d_in[8];
    float* out = (float*)d_out;

    char* ws = (char*)d_ws;
    u16*  Fh  = (u16*)ws;                      // [0,16M)  8192x1024 u16
    u16*  Fl  = (u16*)(ws + 16777216);         // [16,32M)
    float* Gx = (float*)(ws + 33554432);       // [32,160M) 8192x4096 f32
    u16*  Wfh = (u16*)(ws + 33554432);         // [32,40M)  1024x4096 u16, dead at B
    u16*  Wfl = (u16*)(ws + 41943040);         // [40,48M)  dead at B
    char* Wf    = ws;                          // [0,16M)  after pack (post-B)
    char* hfrag = ws + 16777216;               // [16,17M) post-B
    float* c    = (float*)(ws + 17825792);     // [17,17.5M) post-B

    // prep: W_feat = 1024x4096 = 4,194,304 floats = 1,048,576 float4 chunks
    split_pair<<<dim3(4096), dim3(256), 0, stream>>>(W_feat, Wfh, Wfl, 1048576);
    out_init<<<dim3(64), dim3(256), 0, stream>>>(out, b_cls);

    // Phase A: Fh/Fl = split(relu(X @ W_feat^T + b_feat))  M=8192 N=1024 K=4096
    gemm_mfma<false, true, true, true>
        <<<dim3(64, 8), 256, 0, stream>>>(
            x, nullptr, nullptr, 4096,
            nullptr, Wfh, Wfl, 4096, b_feat,
            nullptr, Fh, Fl, 1024, 4096);

    // Phase B: Gx = F @ W_ih^T + b_ih   M=8192 N=4096 K=1024
    gemm_mfma<true, false, false, false>
        <<<dim3(64, 32), 256, 0, stream>>>(
            nullptr, Fh, Fl, 1024,
            W_ih, nullptr, nullptr, 1024, b_ih,
            Gx, nullptr, nullptr, 4096, 1024);

    // pack W_hh fragments AFTER phase B (aliases dead Fh region)
    pack_whh2<<<dim3(2048), dim3(256), 0, stream>>>(W_hh, Wf);

    // Phase C: 64 fused recurrent steps
    for (int t = 0; t < 64; ++t) {
        lstm_step<<<dim3(256), dim3(512), 0, stream>>>(
            Gx, b_hh, Wf, hfrag, c, W_cls, out, t);
    }
}